// Round 4
// baseline (62540.802 us; speedup 1.0000x reference)
//
#include <hip/hip_runtime.h>
#include <stdint.h>

// TLSTM: batch-1 LSTM, T=16384, IN=512, H=1024, OUT=64.
// 256 WGs x 256 threads (1 WG/CU). Wave w of WG b owns h-elem 4b+w and its
// 4 gate rows; weights are PINNED in VGPRs (96 floats/lane) via empty-asm
// "+v" barriers so the allocator cannot rematerialize the loads into the
// t-loop (R1-R3 showed VGPR_Count=72 => weights were being re-read every
// step).
// Cross-WG h exchange: 1024 self-tagged 4-byte words {tag16 | bf16} per
// parity buffer. 16-bit tag works because T=16384 < 65536. Tag travels
// with the data => any load width is safe, no fences, no gather step:
// each wave's lane 0 stores its own word right after combine.
// Consumers poll the WHOLE 4KB state with ONE 16B coherent load per thread
// per round (global_load_dwordx4 sc0 sc1) -- the coalescing minimum of
// 64 line-requests/WG/round.

typedef unsigned int  uint32;
typedef unsigned int  u32x4 __attribute__((ext_vector_type(4)));
typedef float         f32x4 __attribute__((ext_vector_type(4)));

#define T_STEPS 16384
#define IN_DIM  512
#define H_DIM   1024
#define NWG     256
#define WGSZ    256

__device__ __forceinline__ float sigf(float x) {
    return 1.0f / (1.0f + __expf(-x));
}
__device__ __forceinline__ float tanh_fast(float x) {
    return 2.0f / (1.0f + __expf(-2.0f * x)) - 1.0f;
}
__device__ __forceinline__ float dot4(f32x4 a, f32x4 b) {
    return a.x * b.x + a.y * b.y + a.z * b.z + a.w * b.w;
}
__device__ __forceinline__ unsigned f32_to_bf16_bits(float f) {
    unsigned u = __float_as_uint(f);
    return (u + 0x7fffu + ((u >> 16) & 1u)) >> 16;
}
// Device-coherent 16B load (bypasses L1+L2 so cross-XCD stores are seen).
__device__ __forceinline__ u32x4 coh_load16(const uint32* p) {
    u32x4 r;
    asm volatile("global_load_dwordx4 %0, %1, off sc0 sc1\n\t"
                 "s_waitcnt vmcnt(0)"
                 : "=v"(r) : "v"(p) : "memory");
    return r;
}

__global__ __launch_bounds__(WGSZ, 1) void lstm_seq(
    const float* __restrict__ X,
    const float* __restrict__ W_ih,
    const float* __restrict__ W_hh,
    const float* __restrict__ b_ih,
    const float* __restrict__ b_hh,
    uint32* __restrict__ hbuf)   // [2][H_DIM] 4B tagged words in d_ws
{
    const int b    = blockIdx.x;      // 0..255
    const int tid  = threadIdx.x;     // 0..255
    const int w    = tid >> 6;        // wave id 0..3
    const int lane = tid & 63;
    const int elem = 4 * b + w;       // h index this wave produces

    __shared__ float h_lds[2][H_DIM];   // 8 KiB

    // ---- one-time: weights into registers, then PIN them ----
    // lane covers k = c*256 + lane*4 + {0..3}
    f32x4 wh[4][4];   // [gate][chunk] over H_DIM=1024
    f32x4 wx[4][2];   // [gate][chunk] over IN_DIM=512
    float bias_g[4];
    #pragma unroll
    for (int g = 0; g < 4; ++g) {
        const int row = g * H_DIM + elem;
        #pragma unroll
        for (int c = 0; c < 4; ++c)
            wh[g][c] = *(const f32x4*)(W_hh + (size_t)row * H_DIM + (c * 256 + lane * 4));
        #pragma unroll
        for (int c = 0; c < 2; ++c)
            wx[g][c] = *(const f32x4*)(W_ih + (size_t)row * IN_DIM + (c * 256 + lane * 4));
        bias_g[g] = b_ih[row] + b_hh[row];
    }
    // Pin: empty asm makes each value an opaque def -> allocator cannot
    // rematerialize the load inside the t-loop.
    #pragma unroll
    for (int g = 0; g < 4; ++g) {
        #pragma unroll
        for (int c = 0; c < 4; ++c) asm volatile("" : "+v"(wh[g][c]));
        #pragma unroll
        for (int c = 0; c < 2; ++c) asm volatile("" : "+v"(wx[g][c]));
    }

    float c_state = 0.0f;

    for (int t = 0; t < T_STEPS; ++t) {
        const int p = t & 1;
        const unsigned want = (unsigned)t;   // 16-bit tag (t < 16384)

        // ---- X loads first: older vmem ops, drained by the poll's waitcnt,
        //      so their HBM/L2 latency is fully hidden ----
        const float* xrow = X + (size_t)t * IN_DIM;
        const f32x4 xq0 = *(const f32x4*)(xrow + lane * 4);
        const f32x4 xq1 = *(const f32x4*)(xrow + 256 + lane * 4);

        // ---- poll h[t]: ONE 16B coherent load per thread per round ----
        const uint32* src = hbuf + (size_t)p * H_DIM + (tid << 2);
        u32x4 v = coh_load16(src);

        // x-part dots once, between round 1 and any round 2 (off the
        // detection path when >=2 rounds are needed anyway)
        float acc0 = dot4(wx[0][0], xq0) + dot4(wx[0][1], xq1);
        float acc1 = dot4(wx[1][0], xq0) + dot4(wx[1][1], xq1);
        float acc2 = dot4(wx[2][0], xq0) + dot4(wx[2][1], xq1);
        float acc3 = dot4(wx[3][0], xq0) + dot4(wx[3][1], xq1);

        while (((v.x >> 16) ^ want) | ((v.y >> 16) ^ want) |
               ((v.z >> 16) ^ want) | ((v.w >> 16) ^ want)) {
            v = coh_load16(src);
        }

        // unpack 4 bf16 -> contiguous float4 in LDS (conflict-free b128)
        {
            f32x4 hv;
            hv.x = __uint_as_float(v.x << 16);
            hv.y = __uint_as_float(v.y << 16);
            hv.z = __uint_as_float(v.z << 16);
            hv.w = __uint_as_float(v.w << 16);
            *(f32x4*)(&h_lds[p][tid << 2]) = hv;
        }
        __syncthreads();   // the ONLY barrier per step

        // ---- h-part dots ----
        const f32x4* h4 = (const f32x4*)(&h_lds[p][0]);
        #pragma unroll
        for (int c = 0; c < 4; ++c) {
            const f32x4 hv = h4[c * 64 + lane];
            acc0 += dot4(wh[0][c], hv);
            acc1 += dot4(wh[1][c], hv);
            acc2 += dot4(wh[2][c], hv);
            acc3 += dot4(wh[3][c], hv);
        }

        // ---- full-wave butterfly reduce ----
        #pragma unroll
        for (int off = 32; off >= 1; off >>= 1) {
            acc0 += __shfl_xor(acc0, off);
            acc1 += __shfl_xor(acc1, off);
            acc2 += __shfl_xor(acc2, off);
            acc3 += __shfl_xor(acc3, off);
        }

        // ---- combine (uniform across lanes) ----
        const float ii = sigf(acc0 + bias_g[0]);
        const float ff = sigf(acc1 + bias_g[1]);
        const float gg = tanh_fast(acc2 + bias_g[2]);
        const float oo = sigf(acc3 + bias_g[3]);
        const float cn = ff * c_state + ii * gg;
        c_state = cn;
        const float hn = oo * tanh_fast(cn);

        // ---- per-wave immediate store: {tag16=t+1 | bf16(hn)} ----
        if (lane == 0) {
            const uint32 word = (((unsigned)(t + 1)) << 16) | f32_to_bf16_bits(hn);
            __hip_atomic_store(hbuf + (size_t)((t + 1) & 1) * H_DIM + elem,
                               word, __ATOMIC_RELAXED, __HIP_MEMORY_SCOPE_AGENT);
        }
        // No second barrier: a thread can only reach step t+2's h_lds[p]
        // writes after the t+2 poll succeeds, which requires every wave
        // everywhere to have finished step t+1 (and hence step t's reads).
    }
}

__global__ __launch_bounds__(256, 1) void lstm_head(
    const uint32* __restrict__ hbuf,
    const float* __restrict__ W_lin,
    const float* __restrict__ b_lin,
    float* __restrict__ out)
{
    const int tid  = threadIdx.x;
    const int o    = tid >> 2;       // output index, 4 threads per output
    const int part = tid & 3;
    // final h (tag T) lives in parity (T&1)=0; kernel boundary = visibility
    const uint32* src = hbuf + (size_t)(T_STEPS & 1) * H_DIM;

    float sum = 0.f;
    const int k0 = part * 256;
    for (int k = k0; k < k0 + 256; k += 4) {
        const u32x4 v  = *(const u32x4*)(src + k);
        const f32x4 wv = *(const f32x4*)(W_lin + (size_t)o * H_DIM + k);
        sum += wv.x * __uint_as_float(v.x << 16)
             + wv.y * __uint_as_float(v.y << 16)
             + wv.z * __uint_as_float(v.z << 16)
             + wv.w * __uint_as_float(v.w << 16);
    }
    sum += __shfl_xor(sum, 1);
    sum += __shfl_xor(sum, 2);
    if (part == 0)
        out[o] = 1.0f / (1.0f + __expf(-(sum + b_lin[o])));
}

extern "C" void kernel_launch(void* const* d_in, const int* in_sizes, int n_in,
                              void* d_out, int out_size, void* d_ws, size_t ws_size,
                              hipStream_t stream) {
    const float* X     = (const float*)d_in[0];
    // d_in[1] Mask, d_in[2] Delta, d_in[3] dt: unused by the forward pass
    const float* W_ih  = (const float*)d_in[4];
    const float* W_hh  = (const float*)d_in[5];
    const float* b_ih  = (const float*)d_in[6];
    const float* b_hh  = (const float*)d_in[7];
    const float* W_lin = (const float*)d_in[8];
    const float* b_lin = (const float*)d_in[9];
    float* out = (float*)d_out;

    uint32* hbuf = (uint32*)d_ws;   // 2 * 1024 * 4B = 8 KiB used

    // init: both parity buffers = {tag=0, h=0} (all zero bytes)
    hipMemsetAsync(hbuf, 0, 2 * H_DIM * sizeof(uint32), stream);

    lstm_seq<<<NWG, WGSZ, 0, stream>>>(X, W_ih, W_hh, b_ih, b_hh, hbuf);
    lstm_head<<<1, 256, 0, stream>>>(hbuf, W_lin, b_lin, out);
}